// Round 6
// baseline (1570.054 us; speedup 1.0000x reference)
//
#include <hip/hip_runtime.h>

// ---------------------------------------------------------------------------
// CMSFlipLinear: y = x @ W^T, W = ternary * per-128-group scales.
// Round 6: R4's INT8 path (numerics PASSED: absmax 0.375) with the spill bug
// fixed: __launch_bounds__(512) instead of (512,2). R4's (512,2) capped VGPR
// at 128 < the ~240 needed -> accumulator spilled to scratch (WRITE_SIZE
// 3.4 GB, MfmaUtil 3.6%). 8-wave block already implies 2 waves/SIMD (256-reg
// budget); the kernel fits without the cap.
// i8 MFMA = 2x bf16 rate, BK=128 halves LDS traffic per FLOP.
// Schedule = R2's verified race-free 8-phase map (vmcnt(6) @ P4/P8).
// M=8192, N=4096, K=4096.
// ---------------------------------------------------------------------------

typedef int   intx4 __attribute__((ext_vector_type(4)));
typedef float f32x4 __attribute__((ext_vector_type(4)));

constexpr int K  = 4096;
constexpr int N  = 4096;
constexpr int NG = 32;   // groups per output row = K/128

__device__ __forceinline__ unsigned short f2bf(float f) {
  unsigned u = __float_as_uint(f);
  u += 0x7FFFu + ((u >> 16) & 1u);
  return (unsigned short)(u >> 16);
}

__device__ __forceinline__ void gload_lds16(const void* gsrc, void* ldst) {
  const __attribute__((address_space(1))) unsigned* g =
      reinterpret_cast<const __attribute__((address_space(1))) unsigned*>(
          reinterpret_cast<uintptr_t>(gsrc));
  __attribute__((address_space(3))) unsigned* l =
      reinterpret_cast<__attribute__((address_space(3))) unsigned*>(
          reinterpret_cast<uintptr_t>(ldst));
  __builtin_amdgcn_global_load_lds(g, l, 16, 0, 0);
}

// ---- prep 1: x -> i8 with per-row scale ------------------------------------
__global__ __launch_bounds__(256) void quant_x_kernel(const float* __restrict__ x,
                                                      char* __restrict__ q,
                                                      float* __restrict__ sx) {
  const int row = blockIdx.x;
  const int tid = threadIdx.x;
  const float4* xr = reinterpret_cast<const float4*>(x + (long)row * K);
  float4 v[4];
  float am = 0.f;
#pragma unroll
  for (int j = 0; j < 4; ++j) {
    v[j] = xr[tid * 4 + j];
    am = fmaxf(am, fmaxf(fmaxf(fabsf(v[j].x), fabsf(v[j].y)),
                         fmaxf(fabsf(v[j].z), fabsf(v[j].w))));
  }
#pragma unroll
  for (int off = 32; off > 0; off >>= 1)
    am = fmaxf(am, __shfl_xor(am, off));
  __shared__ float wmax[4];
  if ((tid & 63) == 0) wmax[tid >> 6] = am;
  __syncthreads();
  am = fmaxf(fmaxf(wmax[0], wmax[1]), fmaxf(wmax[2], wmax[3]));
  const float inv = am > 0.f ? 127.f / am : 0.f;
  int t[16];
#pragma unroll
  for (int j = 0; j < 4; ++j) {
    t[j * 4 + 0] = (int)rintf(v[j].x * inv);
    t[j * 4 + 1] = (int)rintf(v[j].y * inv);
    t[j * 4 + 2] = (int)rintf(v[j].z * inv);
    t[j * 4 + 3] = (int)rintf(v[j].w * inv);
  }
  int4 o;
  o.x = (t[0] & 255) | ((t[1] & 255) << 8) | ((t[2] & 255) << 16) | ((t[3] & 255) << 24);
  o.y = (t[4] & 255) | ((t[5] & 255) << 8) | ((t[6] & 255) << 16) | ((t[7] & 255) << 24);
  o.z = (t[8] & 255) | ((t[9] & 255) << 8) | ((t[10] & 255) << 16) | ((t[11] & 255) << 24);
  o.w = (t[12] & 255) | ((t[13] & 255) << 8) | ((t[14] & 255) << 16) | ((t[15] & 255) << 24);
  reinterpret_cast<int4*>(q + (long)row * K)[tid] = o;
  if (tid == 0) sx[row] = am * (1.f / 127.f);
}

// ---- prep 2: ternary int32 -> i8 -------------------------------------------
__global__ void pack_w_kernel(const int* __restrict__ w, char* __restrict__ o,
                              long n16) {
  long t = (long)blockIdx.x * blockDim.x + threadIdx.x;
  if (t >= n16) return;
  const int4* src = reinterpret_cast<const int4*>(w + t * 16);
  int4 a = src[0], b = src[1], c = src[2], d = src[3];
  int4 r;
  r.x = (a.x & 255) | ((a.y & 255) << 8) | ((a.z & 255) << 16) | ((a.w & 255) << 24);
  r.y = (b.x & 255) | ((b.y & 255) << 8) | ((b.z & 255) << 16) | ((b.w & 255) << 24);
  r.z = (c.x & 255) | ((c.y & 255) << 8) | ((c.z & 255) << 16) | ((c.w & 255) << 24);
  r.w = (d.x & 255) | ((d.y & 255) << 8) | ((d.z & 255) << 16) | ((d.w & 255) << 24);
  reinterpret_cast<int4*>(o)[t] = r;
}

// ---- prep 3: scales [o][g] f32 -> transposed [g][o] bf16 -------------------
__global__ void cvt_s_kernel(const float* __restrict__ s,
                             unsigned short* __restrict__ o) {
  int t = blockIdx.x * 256 + threadIdx.x;  // 131072 = 32*4096
  int oo = t & (N - 1);
  int g = t >> 12;
  o[t] = f2bf(s[(long)oo * NG + g]);
}

// ---------------------------------------------------------------------------
// GEMM LDS (bytes): a0 [0,32768) | b0 | a1 | b1 | sc [131072,147456)
// Tile = 256 rows x 128 k-bytes. Swizzle: byte = row*128 + (slot ^ ((row&7)<<4)),
// applied on ds_read AND on the global source of linear-dest global_load_lds.
// Read geometry: 16 rows x 8 slots, XOR by row&7 -> conflict-free (R2-verified;
// R4 ran with SQ_LDS_BANK_CONFLICT = 0).
// ---------------------------------------------------------------------------

__device__ __forceinline__ intx4 ldfrag(const char* region, int row, int slot) {
  return *reinterpret_cast<const intx4*>(region + row * 128 +
                                         (slot ^ ((row & 7) << 4)));
}

__device__ __forceinline__ void stage_half(const char* gmat, char* lregion,
                                           int k0, int h, int wid, int l) {
#pragma unroll
  for (int load = 0; load < 2; ++load) {
    const int row = h * 128 + load * 64 + wid * 8 + (l >> 3);
    const int col = ((l & 7) ^ ((l >> 3) & 7)) << 4;
    const char* g = gmat + (long)row * K + k0 + col;
    char* ldst = lregion + h * 16384 + load * 8192 + wid * 1024;  // +lane*16B HW
    gload_lds16(g, ldst);
  }
}

template <int Q>
__device__ __forceinline__ void loadApair(intx4 (&afr)[2][2], const char* ar,
                                          int wr, int rlo, int kq) {
#pragma unroll
  for (int mi = 0; mi < 2; ++mi)
#pragma unroll
    for (int ks = 0; ks < 2; ++ks)
      afr[mi][ks] = ldfrag(ar, wr * 128 + (2 * Q + mi) * 16 + rlo, ks * 64 + kq * 16);
}

__device__ __forceinline__ void loadBall(intx4 (&bfr)[4][2], const char* br,
                                         int wc, int rlo, int kq) {
#pragma unroll
  for (int nt = 0; nt < 4; ++nt)
#pragma unroll
    for (int ks = 0; ks < 2; ++ks)
      bfr[nt][ks] = ldfrag(br, wc * 64 + nt * 16 + rlo, ks * 64 + kq * 16);
}

__device__ __forceinline__ void loadScales(float (&swf)[4], const char* sc,
                                           int T, int wc, int rlo) {
#pragma unroll
  for (int nt = 0; nt < 4; ++nt) {
    unsigned short v = *reinterpret_cast<const unsigned short*>(
        sc + T * 512 + (wc * 64 + nt * 16 + rlo) * 2);
    swf[nt] = __uint_as_float((unsigned)v << 16);
  }
}

template <int Q>
__device__ __forceinline__ void mmaQ(f32x4 (&facc)[8][4], intx4 (&afr)[2][2],
                                     intx4 (&bfr)[4][2], const float (&swf)[4]) {
  __builtin_amdgcn_s_setprio(1);
#pragma unroll
  for (int mi = 0; mi < 2; ++mi)
#pragma unroll
    for (int nt = 0; nt < 4; ++nt) {
      intx4 t = {0, 0, 0, 0};
      t = __builtin_amdgcn_mfma_i32_16x16x64_i8(afr[mi][0], bfr[nt][0], t, 0, 0, 0);
      t = __builtin_amdgcn_mfma_i32_16x16x64_i8(afr[mi][1], bfr[nt][1], t, 0, 0, 0);
#pragma unroll
      for (int r = 0; r < 4; ++r)
        facc[2 * Q + mi][nt][r] += (float)t[r] * swf[nt];
    }
  __builtin_amdgcn_s_setprio(0);
}

#define FENCE asm volatile("" ::: "memory")
#define BAR                       \
  do {                            \
    __builtin_amdgcn_s_barrier(); \
    FENCE;                        \
  } while (0)
#define LGKM0  asm volatile("s_waitcnt lgkmcnt(0)" ::: "memory")
#define VMCNT6 asm volatile("s_waitcnt vmcnt(6)" ::: "memory")
#define VMCNT0 asm volatile("s_waitcnt vmcnt(0)" ::: "memory")

// 256x256x128-tile i8 GEMM, 8 waves (2Mx4N), per-wave 128x64 out.
// Phase/stage/vmcnt map identical to R2/R4 (race-free; R4 numerics passed).
__global__ __launch_bounds__(512) void gemm8p(
    const char* __restrict__ A, const char* __restrict__ B,
    const unsigned short* __restrict__ SWT, const float* __restrict__ SX,
    float* __restrict__ C) {
  __shared__ char lds[147456];  // 144 KiB
  const int tid = threadIdx.x;
  const int wid = tid >> 6, l = tid & 63;
  const int wr = wid >> 2, wc = wid & 3;
  const int rlo = l & 15, kq = l >> 4;

  // T1: bijective XCD swizzle (512 blocks, 512%8==0)
  const int wg = blockIdx.x;
  const int swz = (wg & 7) * 64 + (wg >> 3);
  const long brow = (long)(swz >> 4) * 256;  // 32 M-tiles
  const long bcol = (long)(swz & 15) * 256;  // 16 N-tiles

  const char* gA = A + brow * K;
  const char* gB = B + bcol * K;
  char* a0 = lds;
  char* b0 = lds + 32768;
  char* a1 = lds + 65536;
  char* b1 = lds + 98304;
  char* sc = lds + 131072;  // [32 g][512 B] block's weight scales (bf16)

  // prologue: scale slab (2 loads/wave), then b0,a0 (tile0) + b1,a1-lo (tile1)
#pragma unroll
  for (int j = 0; j < 2; ++j) {
    const int gp = wid * 2 + j;  // 0..15, each covers 2 g-rows
    const unsigned short* src =
        SWT + (size_t)(gp * 2 + (l >> 5)) * N + bcol + (l & 31) * 8;
    gload_lds16(src, sc + gp * 1024);
  }
  stage_half(gB, b0, 0, 0, wid, l);
  stage_half(gB, b0, 0, 1, wid, l);
  stage_half(gA, a0, 0, 0, wid, l);
  stage_half(gA, a0, 0, 1, wid, l);
  stage_half(gB, b1, 128, 0, wid, l);
  stage_half(gB, b1, 128, 1, wid, l);
  stage_half(gA, a1, 128, 0, wid, l);
  VMCNT6;  // drains sc,b0,a0; leaves b1(4)+a1-lo(2) in flight
  BAR;

  f32x4 facc[8][4] = {};
  intx4 afr[2][2], bfr[4][2];
  float swf[4];

#pragma unroll 1
  for (int it = 0; it < 15; ++it) {
    const int kt1 = (2 * it + 1) * 128, kt2 = kt1 + 128, kt3 = kt2 + 128;
    // ---- tile 2it (buf0) ----
    loadBall(bfr, b0, wc, rlo, kq);
    loadApair<0>(afr, a0, wr, rlo, kq);
    loadScales(swf, sc, 2 * it, wc, rlo);
    stage_half(gA, a1, kt1, 1, wid, l);
    BAR; LGKM0;
    mmaQ<0>(facc, afr, bfr, swf);
    BAR;
    loadApair<1>(afr, a0, wr, rlo, kq);
    stage_half(gB, b0, kt2, 0, wid, l);
    BAR; LGKM0;
    mmaQ<1>(facc, afr, bfr, swf);
    BAR;
    loadApair<2>(afr, a0, wr, rlo, kq);
    stage_half(gB, b0, kt2, 1, wid, l);
    BAR; LGKM0;
    mmaQ<2>(facc, afr, bfr, swf);
    BAR;
    loadApair<3>(afr, a0, wr, rlo, kq);
    stage_half(gA, a0, kt2, 0, wid, l);
    BAR; LGKM0;
    mmaQ<3>(facc, afr, bfr, swf);
    VMCNT6;  // tile 2it+1 fully landed
    BAR;
    // ---- tile 2it+1 (buf1) ----
    loadBall(bfr, b1, wc, rlo, kq);
    loadApair<0>(afr, a1, wr, rlo, kq);
    loadScales(swf, sc, 2 * it + 1, wc, rlo);
    stage_half(gA, a0, kt2, 1, wid, l);
    BAR; LGKM0;
    mmaQ<0>(facc, afr, bfr, swf);
    BAR;
    loadApair<1>(afr, a1, wr, rlo, kq);
    stage_half(gB, b1, kt3, 0, wid, l);
    BAR; LGKM0;
    mmaQ<1>(facc, afr, bfr, swf);
    BAR;
    loadApair<2>(afr, a1, wr, rlo, kq);
    stage_half(gB, b1, kt3, 1, wid, l);
    BAR; LGKM0;
    mmaQ<2>(facc, afr, bfr, swf);
    BAR;
    loadApair<3>(afr, a1, wr, rlo, kq);
    stage_half(gA, a1, kt3, 0, wid, l);
    BAR; LGKM0;
    mmaQ<3>(facc, afr, bfr, swf);
    VMCNT6;  // tile 2it+2 fully landed
    BAR;
  }

  // ---- epilogue: tiles 30 (buf0) + 31 (buf1) ----
  loadBall(bfr, b0, wc, rlo, kq);
  loadApair<0>(afr, a0, wr, rlo, kq);
  loadScales(swf, sc, 30, wc, rlo);
  stage_half(gA, a1, 31 * 128, 1, wid, l);  // completes tile 31
  BAR; LGKM0;
  mmaQ<0>(facc, afr, bfr, swf);
  BAR;
  loadApair<1>(afr, a0, wr, rlo, kq);
  BAR; LGKM0;
  mmaQ<1>(facc, afr, bfr, swf);
  BAR;
  loadApair<2>(afr, a0, wr, rlo, kq);
  BAR; LGKM0;
  mmaQ<2>(facc, afr, bfr, swf);
  BAR;
  loadApair<3>(afr, a0, wr, rlo, kq);
  BAR; LGKM0;
  mmaQ<3>(facc, afr, bfr, swf);
  VMCNT0;  // drain tile 31 leftovers
  BAR;
  // tile 31: no more LDS writers
  loadBall(bfr, b1, wc, rlo, kq);
  loadScales(swf, sc, 31, wc, rlo);
  loadApair<0>(afr, a1, wr, rlo, kq);
  LGKM0;
  mmaQ<0>(facc, afr, bfr, swf);
  loadApair<1>(afr, a1, wr, rlo, kq);
  mmaQ<1>(facc, afr, bfr, swf);
  loadApair<2>(afr, a1, wr, rlo, kq);
  mmaQ<2>(facc, afr, bfr, swf);
  loadApair<3>(afr, a1, wr, rlo, kq);
  mmaQ<3>(facc, afr, bfr, swf);

  // C-write: col = lane&15, row = kq*4 + r; apply x row-scale here.
  const long crow0 = brow + wr * 128 + kq * 4;
  const long ccol = bcol + wc * 64 + rlo;
#pragma unroll
  for (int mi = 0; mi < 8; ++mi) {
    const float4 sx4 = *reinterpret_cast<const float4*>(SX + crow0 + mi * 16);
#pragma unroll
    for (int nt = 0; nt < 4; ++nt) {
      float* cp = C + (crow0 + mi * 16) * (long)N + ccol + nt * 16;
      cp[0 * N] = facc[mi][nt][0] * sx4.x;
      cp[1 * N] = facc[mi][nt][1] * sx4.y;
      cp[2 * N] = facc[mi][nt][2] * sx4.z;
      cp[3 * N] = facc[mi][nt][3] * sx4.w;
    }
  }
}

// ---- fallback (only if workspace too small): naive fp32 --------------------
__global__ void fallback_kernel(const float* __restrict__ x,
                                const int* __restrict__ t,
                                const float* __restrict__ s,
                                float* __restrict__ y) {
  int n = blockIdx.x * 256 + threadIdx.x;
  int m = blockIdx.y;
  const int* tr = t + (long)n * K;
  const float* xr = x + (long)m * K;
  float acc = 0.f;
  for (int g = 0; g < K / 128; ++g) {
    float scv = s[n * (K / 128) + g];
    float part = 0.f;
#pragma unroll 4
    for (int k = g * 128; k < g * 128 + 128; ++k)
      part += xr[k] * (float)tr[k];
    acc += part * scv;
  }
  y[(long)m * N + n] = acc;
}

extern "C" void kernel_launch(void* const* d_in, const int* in_sizes, int n_in,
                              void* d_out, int out_size, void* d_ws,
                              size_t ws_size, hipStream_t stream) {
  const float* x = (const float*)d_in[0];
  const int* tern = (const int*)d_in[1];
  const float* scales = (const float*)d_in[2];
  float* out = (float*)d_out;

  const long M = (long)in_sizes[0] / K;  // 8192
  const size_t offW = (size_t)M * K;                 // A_i8: 32 MiB
  const size_t offS = offW + (size_t)N * K;          // W_i8: 16 MiB
  const size_t offX = offS + (size_t)NG * N * 2;     // sw_t bf16: 256 KiB
  const size_t need = offX + (size_t)M * 4;          // s_x f32

  if (ws_size >= need && (M % 256) == 0) {
    char* Aq = (char*)d_ws;
    char* Wq = (char*)d_ws + offW;
    unsigned short* SWT = (unsigned short*)((char*)d_ws + offS);
    float* SX = (float*)((char*)d_ws + offX);

    quant_x_kernel<<<(unsigned)M, 256, 0, stream>>>(x, Aq, SX);
    const long n16 = (long)N * K / 16;
    pack_w_kernel<<<(unsigned)((n16 + 255) / 256), 256, 0, stream>>>(tern, Wq, n16);
    cvt_s_kernel<<<(unsigned)(NG * N / 256), 256, 0, stream>>>(scales, SWT);

    const unsigned nblk = (unsigned)((M / 256) * (N / 256));  // 512
    gemm8p<<<nblk, 512, 0, stream>>>(Aq, Wq, SWT, SX, out);
  } else {
    dim3 grid(N / 256, (unsigned)M);
    fallback_kernel<<<grid, 256, 0, stream>>>(x, tern, scales, out);
  }
}

// Round 7
// 1561.643 us; speedup vs baseline: 1.0054x; 1.0054x over previous
//
#include <hip/hip_runtime.h>

// ---------------------------------------------------------------------------
// CMSFlipLinear: y = x @ W^T, W = ternary * per-128-group scales.
// Round 7: i8 path, third attempt at the spill. R4/(512,2) and R6/(512) both
// produced VGPR_Count=128 -> 128-float f32 accumulator (VALU-accessed every
// phase, so it cannot live in AGPRs like R2's MFMA-only acc) spilled to
// scratch (WRITE_SIZE 3.4GB, MfmaUtil 3.5%). Fix: explicit
// amdgpu_waves_per_eu(2,2) -> 256-reg budget. LDS 144KiB already limits the
// CU to 1 block (2 waves/SIMD), so this costs no real occupancy.
// i8 MFMA = 2x bf16 rate; BK=128 halves phases per K. Numerics R4-proven
// (absmax 0.375 < 0.725). Schedule = R2's verified race-free 8-phase map.
// M=8192, N=4096, K=4096.
// ---------------------------------------------------------------------------

typedef int   intx4 __attribute__((ext_vector_type(4)));
typedef float f32x4 __attribute__((ext_vector_type(4)));

constexpr int K  = 4096;
constexpr int N  = 4096;
constexpr int NG = 32;   // groups per output row = K/128

__device__ __forceinline__ unsigned short f2bf(float f) {
  unsigned u = __float_as_uint(f);
  u += 0x7FFFu + ((u >> 16) & 1u);
  return (unsigned short)(u >> 16);
}

__device__ __forceinline__ void gload_lds16(const void* gsrc, void* ldst) {
  const __attribute__((address_space(1))) unsigned* g =
      reinterpret_cast<const __attribute__((address_space(1))) unsigned*>(
          reinterpret_cast<uintptr_t>(gsrc));
  __attribute__((address_space(3))) unsigned* l =
      reinterpret_cast<__attribute__((address_space(3))) unsigned*>(
          reinterpret_cast<uintptr_t>(ldst));
  __builtin_amdgcn_global_load_lds(g, l, 16, 0, 0);
}

// ---- prep 1: x -> i8 with per-row scale ------------------------------------
__global__ __launch_bounds__(256) void quant_x_kernel(const float* __restrict__ x,
                                                      char* __restrict__ q,
                                                      float* __restrict__ sx) {
  const int row = blockIdx.x;
  const int tid = threadIdx.x;
  const float4* xr = reinterpret_cast<const float4*>(x + (long)row * K);
  float4 v[4];
  float am = 0.f;
#pragma unroll
  for (int j = 0; j < 4; ++j) {
    v[j] = xr[tid * 4 + j];
    am = fmaxf(am, fmaxf(fmaxf(fabsf(v[j].x), fabsf(v[j].y)),
                         fmaxf(fabsf(v[j].z), fabsf(v[j].w))));
  }
#pragma unroll
  for (int off = 32; off > 0; off >>= 1)
    am = fmaxf(am, __shfl_xor(am, off));
  __shared__ float wmax[4];
  if ((tid & 63) == 0) wmax[tid >> 6] = am;
  __syncthreads();
  am = fmaxf(fmaxf(wmax[0], wmax[1]), fmaxf(wmax[2], wmax[3]));
  const float inv = am > 0.f ? 127.f / am : 0.f;
  int t[16];
#pragma unroll
  for (int j = 0; j < 4; ++j) {
    t[j * 4 + 0] = (int)rintf(v[j].x * inv);
    t[j * 4 + 1] = (int)rintf(v[j].y * inv);
    t[j * 4 + 2] = (int)rintf(v[j].z * inv);
    t[j * 4 + 3] = (int)rintf(v[j].w * inv);
  }
  int4 o;
  o.x = (t[0] & 255) | ((t[1] & 255) << 8) | ((t[2] & 255) << 16) | ((t[3] & 255) << 24);
  o.y = (t[4] & 255) | ((t[5] & 255) << 8) | ((t[6] & 255) << 16) | ((t[7] & 255) << 24);
  o.z = (t[8] & 255) | ((t[9] & 255) << 8) | ((t[10] & 255) << 16) | ((t[11] & 255) << 24);
  o.w = (t[12] & 255) | ((t[13] & 255) << 8) | ((t[14] & 255) << 16) | ((t[15] & 255) << 24);
  reinterpret_cast<int4*>(q + (long)row * K)[tid] = o;
  if (tid == 0) sx[row] = am * (1.f / 127.f);
}

// ---- prep 2: ternary int32 -> i8 -------------------------------------------
__global__ void pack_w_kernel(const int* __restrict__ w, char* __restrict__ o,
                              long n16) {
  long t = (long)blockIdx.x * blockDim.x + threadIdx.x;
  if (t >= n16) return;
  const int4* src = reinterpret_cast<const int4*>(w + t * 16);
  int4 a = src[0], b = src[1], c = src[2], d = src[3];
  int4 r;
  r.x = (a.x & 255) | ((a.y & 255) << 8) | ((a.z & 255) << 16) | ((a.w & 255) << 24);
  r.y = (b.x & 255) | ((b.y & 255) << 8) | ((b.z & 255) << 16) | ((b.w & 255) << 24);
  r.z = (c.x & 255) | ((c.y & 255) << 8) | ((c.z & 255) << 16) | ((c.w & 255) << 24);
  r.w = (d.x & 255) | ((d.y & 255) << 8) | ((d.z & 255) << 16) | ((d.w & 255) << 24);
  reinterpret_cast<int4*>(o)[t] = r;
}

// ---- prep 3: scales [o][g] f32 -> transposed [g][o] bf16 -------------------
__global__ void cvt_s_kernel(const float* __restrict__ s,
                             unsigned short* __restrict__ o) {
  int t = blockIdx.x * 256 + threadIdx.x;  // 131072 = 32*4096
  int oo = t & (N - 1);
  int g = t >> 12;
  o[t] = f2bf(s[(long)oo * NG + g]);
}

// ---------------------------------------------------------------------------
// GEMM LDS (bytes): a0 [0,32768) | b0 | a1 | b1 | sc [131072,147456)
// Tile = 256 rows x 128 k-bytes. Swizzle: byte = row*128 + (slot ^ ((row&7)<<4)),
// applied on ds_read AND on the global source of linear-dest global_load_lds.
// 16 rows x 8 slots, XOR by row&7 -> conflict-free (R4/R6 measured 0).
// ---------------------------------------------------------------------------

__device__ __forceinline__ intx4 ldfrag(const char* region, int row, int slot) {
  return *reinterpret_cast<const intx4*>(region + row * 128 +
                                         (slot ^ ((row & 7) << 4)));
}

__device__ __forceinline__ void stage_half(const char* gmat, char* lregion,
                                           int k0, int h, int wid, int l) {
#pragma unroll
  for (int load = 0; load < 2; ++load) {
    const int row = h * 128 + load * 64 + wid * 8 + (l >> 3);
    const int col = ((l & 7) ^ ((l >> 3) & 7)) << 4;
    const char* g = gmat + (long)row * K + k0 + col;
    char* ldst = lregion + h * 16384 + load * 8192 + wid * 1024;  // +lane*16B HW
    gload_lds16(g, ldst);
  }
}

template <int Q>
__device__ __forceinline__ void loadApair(intx4 (&afr)[2][2], const char* ar,
                                          int wr, int rlo, int kq) {
#pragma unroll
  for (int mi = 0; mi < 2; ++mi)
#pragma unroll
    for (int ks = 0; ks < 2; ++ks)
      afr[mi][ks] = ldfrag(ar, wr * 128 + (2 * Q + mi) * 16 + rlo, ks * 64 + kq * 16);
}

__device__ __forceinline__ void loadBall(intx4 (&bfr)[4][2], const char* br,
                                         int wc, int rlo, int kq) {
#pragma unroll
  for (int nt = 0; nt < 4; ++nt)
#pragma unroll
    for (int ks = 0; ks < 2; ++ks)
      bfr[nt][ks] = ldfrag(br, wc * 64 + nt * 16 + rlo, ks * 64 + kq * 16);
}

__device__ __forceinline__ void loadScales(float (&swf)[4], const char* sc,
                                           int T, int wc, int rlo) {
#pragma unroll
  for (int nt = 0; nt < 4; ++nt) {
    unsigned short v = *reinterpret_cast<const unsigned short*>(
        sc + T * 512 + (wc * 64 + nt * 16 + rlo) * 2);
    swf[nt] = __uint_as_float((unsigned)v << 16);
  }
}

template <int Q>
__device__ __forceinline__ void mmaQ(f32x4 (&facc)[8][4], intx4 (&afr)[2][2],
                                     intx4 (&bfr)[4][2], const float (&swf)[4]) {
  __builtin_amdgcn_s_setprio(1);
#pragma unroll
  for (int mi = 0; mi < 2; ++mi)
#pragma unroll
    for (int nt = 0; nt < 4; ++nt) {
      intx4 t = {0, 0, 0, 0};
      t = __builtin_amdgcn_mfma_i32_16x16x64_i8(afr[mi][0], bfr[nt][0], t, 0, 0, 0);
      t = __builtin_amdgcn_mfma_i32_16x16x64_i8(afr[mi][1], bfr[nt][1], t, 0, 0, 0);
#pragma unroll
      for (int r = 0; r < 4; ++r)
        facc[2 * Q + mi][nt][r] += (float)t[r] * swf[nt];
    }
  __builtin_amdgcn_s_setprio(0);
}

#define FENCE asm volatile("" ::: "memory")
#define BAR                       \
  do {                            \
    __builtin_amdgcn_s_barrier(); \
    FENCE;                        \
  } while (0)
#define LGKM0  asm volatile("s_waitcnt lgkmcnt(0)" ::: "memory")
#define VMCNT6 asm volatile("s_waitcnt vmcnt(6)" ::: "memory")
#define VMCNT0 asm volatile("s_waitcnt vmcnt(0)" ::: "memory")

// 256x256x128-tile i8 GEMM, 8 waves (2Mx4N), per-wave 128x64 out.
// amdgpu_waves_per_eu(2,2): 256-reg budget (the spill fix). LDS caps the CU
// at 1 block = 2 waves/SIMD regardless, so no occupancy is lost.
__global__ __launch_bounds__(512)
__attribute__((amdgpu_waves_per_eu(2, 2))) void gemm8p(
    const char* __restrict__ A, const char* __restrict__ B,
    const unsigned short* __restrict__ SWT, const float* __restrict__ SX,
    float* __restrict__ C) {
  __shared__ char lds[147456];  // 144 KiB
  const int tid = threadIdx.x;
  const int wid = tid >> 6, l = tid & 63;
  const int wr = wid >> 2, wc = wid & 3;
  const int rlo = l & 15, kq = l >> 4;

  // T1: bijective XCD swizzle (512 blocks, 512%8==0)
  const int wg = blockIdx.x;
  const int swz = (wg & 7) * 64 + (wg >> 3);
  const long brow = (long)(swz >> 4) * 256;  // 32 M-tiles
  const long bcol = (long)(swz & 15) * 256;  // 16 N-tiles

  const char* gA = A + brow * K;
  const char* gB = B + bcol * K;
  char* a0 = lds;
  char* b0 = lds + 32768;
  char* a1 = lds + 65536;
  char* b1 = lds + 98304;
  char* sc = lds + 131072;  // [32 g][512 B] block's weight scales (bf16)

  // prologue: scale slab (2 loads/wave), then b0,a0 (tile0) + b1,a1-lo (tile1)
#pragma unroll
  for (int j = 0; j < 2; ++j) {
    const int gp = wid * 2 + j;  // 0..15, each covers 2 g-rows
    const unsigned short* src =
        SWT + (size_t)(gp * 2 + (l >> 5)) * N + bcol + (l & 31) * 8;
    gload_lds16(src, sc + gp * 1024);
  }
  stage_half(gB, b0, 0, 0, wid, l);
  stage_half(gB, b0, 0, 1, wid, l);
  stage_half(gA, a0, 0, 0, wid, l);
  stage_half(gA, a0, 0, 1, wid, l);
  stage_half(gB, b1, 128, 0, wid, l);
  stage_half(gB, b1, 128, 1, wid, l);
  stage_half(gA, a1, 128, 0, wid, l);
  VMCNT6;  // drains sc,b0,a0; leaves b1(4)+a1-lo(2) in flight
  BAR;

  f32x4 facc[8][4] = {};
  intx4 afr[2][2], bfr[4][2];
  float swf[4];

#pragma unroll 1
  for (int it = 0; it < 15; ++it) {
    const int kt1 = (2 * it + 1) * 128, kt2 = kt1 + 128, kt3 = kt2 + 128;
    // ---- tile 2it (buf0) ----
    loadBall(bfr, b0, wc, rlo, kq);
    loadApair<0>(afr, a0, wr, rlo, kq);
    loadScales(swf, sc, 2 * it, wc, rlo);
    stage_half(gA, a1, kt1, 1, wid, l);
    BAR; LGKM0;
    mmaQ<0>(facc, afr, bfr, swf);
    BAR;
    loadApair<1>(afr, a0, wr, rlo, kq);
    stage_half(gB, b0, kt2, 0, wid, l);
    BAR; LGKM0;
    mmaQ<1>(facc, afr, bfr, swf);
    BAR;
    loadApair<2>(afr, a0, wr, rlo, kq);
    stage_half(gB, b0, kt2, 1, wid, l);
    BAR; LGKM0;
    mmaQ<2>(facc, afr, bfr, swf);
    BAR;
    loadApair<3>(afr, a0, wr, rlo, kq);
    stage_half(gA, a0, kt2, 0, wid, l);
    BAR; LGKM0;
    mmaQ<3>(facc, afr, bfr, swf);
    VMCNT6;  // tile 2it+1 fully landed
    BAR;
    // ---- tile 2it+1 (buf1) ----
    loadBall(bfr, b1, wc, rlo, kq);
    loadApair<0>(afr, a1, wr, rlo, kq);
    loadScales(swf, sc, 2 * it + 1, wc, rlo);
    stage_half(gA, a0, kt2, 1, wid, l);
    BAR; LGKM0;
    mmaQ<0>(facc, afr, bfr, swf);
    BAR;
    loadApair<1>(afr, a1, wr, rlo, kq);
    stage_half(gB, b1, kt3, 0, wid, l);
    BAR; LGKM0;
    mmaQ<1>(facc, afr, bfr, swf);
    BAR;
    loadApair<2>(afr, a1, wr, rlo, kq);
    stage_half(gB, b1, kt3, 1, wid, l);
    BAR; LGKM0;
    mmaQ<2>(facc, afr, bfr, swf);
    BAR;
    loadApair<3>(afr, a1, wr, rlo, kq);
    stage_half(gA, a1, kt3, 0, wid, l);
    BAR; LGKM0;
    mmaQ<3>(facc, afr, bfr, swf);
    VMCNT6;  // tile 2it+2 fully landed
    BAR;
  }

  // ---- epilogue: tiles 30 (buf0) + 31 (buf1) ----
  loadBall(bfr, b0, wc, rlo, kq);
  loadApair<0>(afr, a0, wr, rlo, kq);
  loadScales(swf, sc, 30, wc, rlo);
  stage_half(gA, a1, 31 * 128, 1, wid, l);  // completes tile 31
  BAR; LGKM0;
  mmaQ<0>(facc, afr, bfr, swf);
  BAR;
  loadApair<1>(afr, a0, wr, rlo, kq);
  BAR; LGKM0;
  mmaQ<1>(facc, afr, bfr, swf);
  BAR;
  loadApair<2>(afr, a0, wr, rlo, kq);
  BAR; LGKM0;
  mmaQ<2>(facc, afr, bfr, swf);
  BAR;
  loadApair<3>(afr, a0, wr, rlo, kq);
  BAR; LGKM0;
  mmaQ<3>(facc, afr, bfr, swf);
  VMCNT0;  // drain tile 31 leftovers
  BAR;
  // tile 31: no more LDS writers
  loadBall(bfr, b1, wc, rlo, kq);
  loadScales(swf, sc, 31, wc, rlo);
  loadApair<0>(afr, a1, wr, rlo, kq);
  LGKM0;
  mmaQ<0>(facc, afr, bfr, swf);
  loadApair<1>(afr, a1, wr, rlo, kq);
  mmaQ<1>(facc, afr, bfr, swf);
  loadApair<2>(afr, a1, wr, rlo, kq);
  mmaQ<2>(facc, afr, bfr, swf);
  loadApair<3>(afr, a1, wr, rlo, kq);
  mmaQ<3>(facc, afr, bfr, swf);

  // C-write: col = lane&15, row = kq*4 + r; apply x row-scale here.
  const long crow0 = brow + wr * 128 + kq * 4;
  const long ccol = bcol + wc * 64 + rlo;
#pragma unroll
  for (int mi = 0; mi < 8; ++mi) {
    const float4 sx4 = *reinterpret_cast<const float4*>(SX + crow0 + mi * 16);
#pragma unroll
    for (int nt = 0; nt < 4; ++nt) {
      float* cp = C + (crow0 + mi * 16) * (long)N + ccol + nt * 16;
      cp[0 * N] = facc[mi][nt][0] * sx4.x;
      cp[1 * N] = facc[mi][nt][1] * sx4.y;
      cp[2 * N] = facc[mi][nt][2] * sx4.z;
      cp[3 * N] = facc[mi][nt][3] * sx4.w;
    }
  }
}

// ---- fallback (only if workspace too small): naive fp32 --------------------
__global__ void fallback_kernel(const float* __restrict__ x,
                                const int* __restrict__ t,
                                const float* __restrict__ s,
                                float* __restrict__ y) {
  int n = blockIdx.x * 256 + threadIdx.x;
  int m = blockIdx.y;
  const int* tr = t + (long)n * K;
  const float* xr = x + (long)m * K;
  float acc = 0.f;
  for (int g = 0; g < K / 128; ++g) {
    float scv = s[n * (K / 128) + g];
    float part = 0.f;
#pragma unroll 4
    for (int k = g * 128; k < g * 128 + 128; ++k)
      part += xr[k] * (float)tr[k];
    acc += part * scv;
  }
  y[(long)m * N + n] = acc;
}

extern "C" void kernel_launch(void* const* d_in, const int* in_sizes, int n_in,
                              void* d_out, int out_size, void* d_ws,
                              size_t ws_size, hipStream_t stream) {
  const float* x = (const float*)d_in[0];
  const int* tern = (const int*)d_in[1];
  const float* scales = (const float*)d_in[2];
  float* out = (float*)d_out;

  const long M = (long)in_sizes[0] / K;  // 8192
  const size_t offW = (size_t)M * K;                 // A_i8: 32 MiB
  const size_t offS = offW + (size_t)N * K;          // W_i8: 16 MiB
  const size_t offX = offS + (size_t)NG * N * 2;     // sw_t bf16: 256 KiB
  const size_t need = offX + (size_t)M * 4;          // s_x f32

  if (ws_size >= need && (M % 256) == 0) {
    char* Aq = (char*)d_ws;
    char* Wq = (char*)d_ws + offW;
    unsigned short* SWT = (unsigned short*)((char*)d_ws + offS);
    float* SX = (float*)((char*)d_ws + offX);

    quant_x_kernel<<<(unsigned)M, 256, 0, stream>>>(x, Aq, SX);
    const long n16 = (long)N * K / 16;
    pack_w_kernel<<<(unsigned)((n16 + 255) / 256), 256, 0, stream>>>(tern, Wq, n16);
    cvt_s_kernel<<<(unsigned)(NG * N / 256), 256, 0, stream>>>(scales, SWT);

    const unsigned nblk = (unsigned)((M / 256) * (N / 256));  // 512
    gemm8p<<<nblk, 512, 0, stream>>>(Aq, Wq, SWT, SX, out);
  } else {
    dim3 grid(N / 256, (unsigned)M);
    fallback_kernel<<<grid, 256, 0, stream>>>(x, tern, scales, out);
  }
}

// Round 8
// 180.122 us; speedup vs baseline: 8.7166x; 8.6699x over previous
//
#include <hip/hip_runtime.h>

// ---------------------------------------------------------------------------
// CMSFlipLinear: y = x @ W^T, W = ternary * per-128-group scales.
// Round 8: i8 path with MFMA-ONLY i32 accumulator (the spill fix).
// R4/R6/R7 spilled because the f32 accumulator was VALU-updated every phase
// and could not live in AGPRs (backend budgets ~128 arch VGPRs). Fix:
// absorb group scales into the weights: wq = tern * round(127*s_w/S_o),
// y = (S_o/127)*s_x[m]*sum(xq*wq). K-loop = pure i8 MFMA -> acc in AGPRs
// (R2 pattern); scales applied once in the epilogue.
// Schedule = R2's verified race-free 8-phase map (bytes); swizzle geometry
// ran at 0 bank conflicts in R4/R6/R7. M=8192, N=4096, K=4096.
// ---------------------------------------------------------------------------

typedef int intx4 __attribute__((ext_vector_type(4)));

constexpr int K  = 4096;
constexpr int N  = 4096;
constexpr int NG = 32;   // groups per output row = K/128

__device__ __forceinline__ void gload_lds16(const void* gsrc, void* ldst) {
  const __attribute__((address_space(1))) unsigned* g =
      reinterpret_cast<const __attribute__((address_space(1))) unsigned*>(
          reinterpret_cast<uintptr_t>(gsrc));
  __attribute__((address_space(3))) unsigned* l =
      reinterpret_cast<__attribute__((address_space(3))) unsigned*>(
          reinterpret_cast<uintptr_t>(ldst));
  __builtin_amdgcn_global_load_lds(g, l, 16, 0, 0);
}

// ---- prep 1: x -> i8 with per-row scale ------------------------------------
__global__ __launch_bounds__(256) void quant_x_kernel(const float* __restrict__ x,
                                                      char* __restrict__ q,
                                                      float* __restrict__ sx) {
  const int row = blockIdx.x;
  const int tid = threadIdx.x;
  const float4* xr = reinterpret_cast<const float4*>(x + (long)row * K);
  float4 v[4];
  float am = 0.f;
#pragma unroll
  for (int j = 0; j < 4; ++j) {
    v[j] = xr[tid * 4 + j];
    am = fmaxf(am, fmaxf(fmaxf(fabsf(v[j].x), fabsf(v[j].y)),
                         fmaxf(fabsf(v[j].z), fabsf(v[j].w))));
  }
#pragma unroll
  for (int off = 32; off > 0; off >>= 1)
    am = fmaxf(am, __shfl_xor(am, off));
  __shared__ float wmax[4];
  if ((tid & 63) == 0) wmax[tid >> 6] = am;
  __syncthreads();
  am = fmaxf(fmaxf(wmax[0], wmax[1]), fmaxf(wmax[2], wmax[3]));
  const float inv = am > 0.f ? 127.f / am : 0.f;
  int t[16];
#pragma unroll
  for (int j = 0; j < 4; ++j) {
    t[j * 4 + 0] = (int)rintf(v[j].x * inv);
    t[j * 4 + 1] = (int)rintf(v[j].y * inv);
    t[j * 4 + 2] = (int)rintf(v[j].z * inv);
    t[j * 4 + 3] = (int)rintf(v[j].w * inv);
  }
  int4 o;
  o.x = (t[0] & 255) | ((t[1] & 255) << 8) | ((t[2] & 255) << 16) | ((t[3] & 255) << 24);
  o.y = (t[4] & 255) | ((t[5] & 255) << 8) | ((t[6] & 255) << 16) | ((t[7] & 255) << 24);
  o.z = (t[8] & 255) | ((t[9] & 255) << 8) | ((t[10] & 255) << 16) | ((t[11] & 255) << 24);
  o.w = (t[12] & 255) | ((t[13] & 255) << 8) | ((t[14] & 255) << 16) | ((t[15] & 255) << 24);
  reinterpret_cast<int4*>(q + (long)row * K)[tid] = o;
  if (tid == 0) sx[row] = am * (1.f / 127.f);
}

// ---- prep 2: wq = tern * round(127*s/S_row); sw[row] = S_row/127 -----------
__global__ __launch_bounds__(256) void pack_w_kernel(const int* __restrict__ w,
                                                     const float* __restrict__ s,
                                                     char* __restrict__ o,
                                                     float* __restrict__ sw) {
  const int row = blockIdx.x;
  const int tid = threadIdx.x;
  __shared__ float Ssh;
  if (tid < 64) {
    float v = (tid < NG) ? s[(long)row * NG + tid] : 0.f;
#pragma unroll
    for (int off = 32; off > 0; off >>= 1)
      v = fmaxf(v, __shfl_xor(v, off));
    if (tid == 0) {
      Ssh = v;
      sw[row] = v * (1.f / 127.f);
    }
  }
  __syncthreads();
  const float S = Ssh;
  const int g = tid >> 3;  // 16 weights/thread -> group = tid*16/128
  const int m = (int)rintf(127.f * s[(long)row * NG + g] / S);
  const int4* src = reinterpret_cast<const int4*>(w + (long)row * K + tid * 16);
  int4 a = src[0], b = src[1], c = src[2], d = src[3];
  int4 r;
  r.x = ((a.x * m) & 255) | (((a.y * m) & 255) << 8) |
        (((a.z * m) & 255) << 16) | (((a.w * m) & 255) << 24);
  r.y = ((b.x * m) & 255) | (((b.y * m) & 255) << 8) |
        (((b.z * m) & 255) << 16) | (((b.w * m) & 255) << 24);
  r.z = ((c.x * m) & 255) | (((c.y * m) & 255) << 8) |
        (((c.z * m) & 255) << 16) | (((c.w * m) & 255) << 24);
  r.w = ((d.x * m) & 255) | (((d.y * m) & 255) << 8) |
        (((d.z * m) & 255) << 16) | (((d.w * m) & 255) << 24);
  reinterpret_cast<int4*>(o + (long)row * K)[tid] = r;
}

// ---------------------------------------------------------------------------
// GEMM LDS (bytes): a0 [0,32768) | b0 | a1 | b1  (128 KiB).
// Tile = 256 rows x 128 k-bytes. Swizzle: byte = row*128 + (slot ^ ((row&7)<<4)),
// on ds_read AND on the global source of linear-dest global_load_lds
// (rule #21). 16 rows x 8 slots, XOR by row&7 -> conflict-free (measured 0
// in R4/R6/R7).
// ---------------------------------------------------------------------------

__device__ __forceinline__ intx4 ldfrag(const char* region, int row, int slot) {
  return *reinterpret_cast<const intx4*>(region + row * 128 +
                                         (slot ^ ((row & 7) << 4)));
}

__device__ __forceinline__ void stage_half(const char* gmat, char* lregion,
                                           int k0, int h, int wid, int l) {
#pragma unroll
  for (int load = 0; load < 2; ++load) {
    const int row = h * 128 + load * 64 + wid * 8 + (l >> 3);
    const int col = ((l & 7) ^ ((l >> 3) & 7)) << 4;
    const char* g = gmat + (long)row * K + k0 + col;
    char* ldst = lregion + h * 16384 + load * 8192 + wid * 1024;  // +lane*16B HW
    gload_lds16(g, ldst);
  }
}

template <int Q>
__device__ __forceinline__ void loadApair(intx4 (&afr)[2][2], const char* ar,
                                          int wr, int rlo, int kq) {
#pragma unroll
  for (int mi = 0; mi < 2; ++mi)
#pragma unroll
    for (int ks = 0; ks < 2; ++ks)
      afr[mi][ks] = ldfrag(ar, wr * 128 + (2 * Q + mi) * 16 + rlo,
                           ks * 64 + kq * 16);
}

__device__ __forceinline__ void loadBall(intx4 (&bfr)[4][2], const char* br,
                                         int wc, int rlo, int kq) {
#pragma unroll
  for (int nt = 0; nt < 4; ++nt)
#pragma unroll
    for (int ks = 0; ks < 2; ++ks)
      bfr[nt][ks] = ldfrag(br, wc * 64 + nt * 16 + rlo, ks * 64 + kq * 16);
}

// Pure MFMA accumulate: acc is NEVER touched by VALU inside the loop ->
// lives in AGPRs (R2 pattern, no arch-VGPR pressure, no spill).
template <int Q>
__device__ __forceinline__ void mmaQ(intx4 (&acc)[8][4], intx4 (&afr)[2][2],
                                     intx4 (&bfr)[4][2]) {
  __builtin_amdgcn_s_setprio(1);
#pragma unroll
  for (int mi = 0; mi < 2; ++mi)
#pragma unroll
    for (int nt = 0; nt < 4; ++nt) {
      acc[2 * Q + mi][nt] = __builtin_amdgcn_mfma_i32_16x16x64_i8(
          afr[mi][0], bfr[nt][0], acc[2 * Q + mi][nt], 0, 0, 0);
      acc[2 * Q + mi][nt] = __builtin_amdgcn_mfma_i32_16x16x64_i8(
          afr[mi][1], bfr[nt][1], acc[2 * Q + mi][nt], 0, 0, 0);
    }
  __builtin_amdgcn_s_setprio(0);
}

#define FENCE asm volatile("" ::: "memory")
#define BAR                       \
  do {                            \
    __builtin_amdgcn_s_barrier(); \
    FENCE;                        \
  } while (0)
#define LGKM0  asm volatile("s_waitcnt lgkmcnt(0)" ::: "memory")
#define VMCNT6 asm volatile("s_waitcnt vmcnt(6)" ::: "memory")
#define VMCNT0 asm volatile("s_waitcnt vmcnt(0)" ::: "memory")

// 256x256x128-tile i8 GEMM, 8 waves (2Mx4N), per-wave 128x64 out.
// Phase/stage/vmcnt map identical to R2 (verified race-free over 3 rounds).
__global__ __launch_bounds__(512) void gemm8p(
    const char* __restrict__ A, const char* __restrict__ B,
    const float* __restrict__ SW, const float* __restrict__ SX,
    float* __restrict__ C) {
  __shared__ char lds[131072];  // 128 KiB
  const int tid = threadIdx.x;
  const int wid = tid >> 6, l = tid & 63;
  const int wr = wid >> 2, wc = wid & 3;
  const int rlo = l & 15, kq = l >> 4;

  // T1: bijective XCD swizzle (512 blocks, 512%8==0)
  const int wg = blockIdx.x;
  const int swz = (wg & 7) * 64 + (wg >> 3);
  const long brow = (long)(swz >> 4) * 256;  // 32 M-tiles
  const long bcol = (long)(swz & 15) * 256;  // 16 N-tiles

  const char* gA = A + brow * K;
  const char* gB = B + bcol * K;
  char* a0 = lds;
  char* b0 = lds + 32768;
  char* a1 = lds + 65536;
  char* b1 = lds + 98304;

  // prologue: b0,a0 (tile0) + b1,a1-lo (tile1)
  stage_half(gB, b0, 0, 0, wid, l);
  stage_half(gB, b0, 0, 1, wid, l);
  stage_half(gA, a0, 0, 0, wid, l);
  stage_half(gA, a0, 0, 1, wid, l);
  stage_half(gB, b1, 128, 0, wid, l);
  stage_half(gB, b1, 128, 1, wid, l);
  stage_half(gA, a1, 128, 0, wid, l);
  VMCNT6;  // drains b0,a0; leaves b1(4)+a1-lo(2) in flight
  BAR;

  intx4 acc[8][4] = {};
  intx4 afr[2][2], bfr[4][2];

#pragma unroll 1
  for (int it = 0; it < 15; ++it) {
    const int kt1 = (2 * it + 1) * 128, kt2 = kt1 + 128, kt3 = kt2 + 128;
    // ---- tile 2it (buf0) ----
    loadBall(bfr, b0, wc, rlo, kq);
    loadApair<0>(afr, a0, wr, rlo, kq);
    stage_half(gA, a1, kt1, 1, wid, l);
    BAR; LGKM0;
    mmaQ<0>(acc, afr, bfr);
    BAR;
    loadApair<1>(afr, a0, wr, rlo, kq);
    stage_half(gB, b0, kt2, 0, wid, l);
    BAR; LGKM0;
    mmaQ<1>(acc, afr, bfr);
    BAR;
    loadApair<2>(afr, a0, wr, rlo, kq);
    stage_half(gB, b0, kt2, 1, wid, l);
    BAR; LGKM0;
    mmaQ<2>(acc, afr, bfr);
    BAR;
    loadApair<3>(afr, a0, wr, rlo, kq);
    stage_half(gA, a0, kt2, 0, wid, l);
    BAR; LGKM0;
    mmaQ<3>(acc, afr, bfr);
    VMCNT6;  // a1@kt1 + prev-b1 landed; b0@kt2 + a0-lo@kt2 in flight
    BAR;
    // ---- tile 2it+1 (buf1) ----
    loadBall(bfr, b1, wc, rlo, kq);
    loadApair<0>(afr, a1, wr, rlo, kq);
    stage_half(gA, a0, kt2, 1, wid, l);
    BAR; LGKM0;
    mmaQ<0>(acc, afr, bfr);
    BAR;
    loadApair<1>(afr, a1, wr, rlo, kq);
    stage_half(gB, b1, kt3, 0, wid, l);
    BAR; LGKM0;
    mmaQ<1>(acc, afr, bfr);
    BAR;
    loadApair<2>(afr, a1, wr, rlo, kq);
    stage_half(gB, b1, kt3, 1, wid, l);
    BAR; LGKM0;
    mmaQ<2>(acc, afr, bfr);
    BAR;
    loadApair<3>(afr, a1, wr, rlo, kq);
    stage_half(gA, a1, kt3, 0, wid, l);
    BAR; LGKM0;
    mmaQ<3>(acc, afr, bfr);
    VMCNT6;  // b0@kt2 + a0@kt2 landed; b1@kt3 + a1-lo@kt3 in flight
    BAR;
  }

  // ---- epilogue: tiles 30 (buf0) + 31 (buf1) ----
  loadBall(bfr, b0, wc, rlo, kq);
  loadApair<0>(afr, a0, wr, rlo, kq);
  stage_half(gA, a1, 31 * 128, 1, wid, l);  // completes tile 31
  BAR; LGKM0;
  mmaQ<0>(acc, afr, bfr);
  BAR;
  loadApair<1>(afr, a0, wr, rlo, kq);
  BAR; LGKM0;
  mmaQ<1>(acc, afr, bfr);
  BAR;
  loadApair<2>(afr, a0, wr, rlo, kq);
  BAR; LGKM0;
  mmaQ<2>(acc, afr, bfr);
  BAR;
  loadApair<3>(afr, a0, wr, rlo, kq);
  BAR; LGKM0;
  mmaQ<3>(acc, afr, bfr);
  VMCNT0;  // drain tile 31 leftovers
  BAR;
  // tile 31: no more LDS writers
  loadBall(bfr, b1, wc, rlo, kq);
  loadApair<0>(afr, a1, wr, rlo, kq);
  LGKM0;
  mmaQ<0>(acc, afr, bfr);
  loadApair<1>(afr, a1, wr, rlo, kq);
  mmaQ<1>(acc, afr, bfr);
  loadApair<2>(afr, a1, wr, rlo, kq);
  mmaQ<2>(acc, afr, bfr);
  loadApair<3>(afr, a1, wr, rlo, kq);
  mmaQ<3>(acc, afr, bfr);

  // Epilogue: y = acc * SX[row] * SW[col]. col = lane&15, row = kq*4 + r.
  const long crow0 = brow + wr * 128 + kq * 4;
  const long ccol = bcol + wc * 64 + rlo;
  float swn[4];
#pragma unroll
  for (int nt = 0; nt < 4; ++nt) swn[nt] = SW[ccol + nt * 16];
#pragma unroll
  for (int mi = 0; mi < 8; ++mi) {
    const float4 sx4 = *reinterpret_cast<const float4*>(SX + crow0 + mi * 16);
    const float sxr[4] = {sx4.x, sx4.y, sx4.z, sx4.w};
#pragma unroll
    for (int nt = 0; nt < 4; ++nt) {
      float* cp = C + (crow0 + mi * 16) * (long)N + ccol + nt * 16;
#pragma unroll
      for (int r = 0; r < 4; ++r)
        cp[r * N] = (float)acc[mi][nt][r] * sxr[r] * swn[nt];
    }
  }
}

// ---- fallback (only if workspace too small): naive fp32 --------------------
__global__ void fallback_kernel(const float* __restrict__ x,
                                const int* __restrict__ t,
                                const float* __restrict__ s,
                                float* __restrict__ y) {
  int n = blockIdx.x * 256 + threadIdx.x;
  int m = blockIdx.y;
  const int* tr = t + (long)n * K;
  const float* xr = x + (long)m * K;
  float acc = 0.f;
  for (int g = 0; g < K / 128; ++g) {
    float scv = s[n * (K / 128) + g];
    float part = 0.f;
#pragma unroll 4
    for (int k = g * 128; k < g * 128 + 128; ++k)
      part += xr[k] * (float)tr[k];
    acc += part * scv;
  }
  y[(long)m * N + n] = acc;
}

extern "C" void kernel_launch(void* const* d_in, const int* in_sizes, int n_in,
                              void* d_out, int out_size, void* d_ws,
                              size_t ws_size, hipStream_t stream) {
  const float* x = (const float*)d_in[0];
  const int* tern = (const int*)d_in[1];
  const float* scales = (const float*)d_in[2];
  float* out = (float*)d_out;

  const long M = (long)in_sizes[0] / K;  // 8192
  const size_t offW = (size_t)M * K;              // A_i8: 32 MiB
  const size_t offSW = offW + (size_t)N * K;      // W_i8: 16 MiB
  const size_t offSX = offSW + (size_t)N * 4;     // SW f32: 16 KiB
  const size_t need = offSX + (size_t)M * 4;      // SX f32: 32 KiB

  if (ws_size >= need && (M % 256) == 0) {
    char* Aq = (char*)d_ws;
    char* Wq = (char*)d_ws + offW;
    float* SW = (float*)((char*)d_ws + offSW);
    float* SX = (float*)((char*)d_ws + offSX);

    quant_x_kernel<<<(unsigned)M, 256, 0, stream>>>(x, Aq, SX);
    pack_w_kernel<<<(unsigned)N, 256, 0, stream>>>(tern, scales, Wq, SW);

    const unsigned nblk = (unsigned)((M / 256) * (N / 256));  // 512
    gemm8p<<<nblk, 512, 0, stream>>>(Aq, Wq, SW, SX, out);
  } else {
    dim3 grid(N / 256, (unsigned)M);
    fallback_kernel<<<grid, 256, 0, stream>>>(x, tern, scales, out);
  }
}